// Round 1
// baseline (634.302 us; speedup 1.0000x reference)
//
#include <hip/hip_runtime.h>

#define B 256
#define LAT 20
#define HID 128
#define G 25000
#define GB 1000
#define NC 7

typedef __attribute__((ext_vector_type(8))) short short8;
typedef __attribute__((ext_vector_type(4))) float f32x4;

__device__ __forceinline__ unsigned short f2bf(float f) {
  unsigned int u = __float_as_uint(f);
  u += 0x7fffu + ((u >> 16) & 1u);   // round-to-nearest-even
  return (unsigned short)(u >> 16);
}

// threefry2x32 with key (0,42), x0=0 (hi word of flat index), x1=idx (lo word),
// partitionable-mode output fold o0^o1. ks = [0, 42, 0x1BD11BF0].
__device__ __forceinline__ unsigned int threefry_xor(unsigned int idx) {
  unsigned int x0 = 0u;
  unsigned int x1 = idx + 42u;
#define TF_R(r) { x0 += x1; x1 = (x1 << r) | (x1 >> (32 - r)); x1 ^= x0; }
  TF_R(13) TF_R(15) TF_R(26) TF_R(6)
  x0 += 42u;          x1 += 0x1BD11BF1u;   // ks2+1
  TF_R(17) TF_R(29) TF_R(16) TF_R(24)
  x0 += 0x1BD11BF0u;  x1 += 2u;            // ks0+2
  TF_R(13) TF_R(15) TF_R(26) TF_R(6)
  /* x0 += ks0 = 0 */ x1 += 45u;           // ks1+3
  TF_R(17) TF_R(29) TF_R(16) TF_R(24)
  x0 += 42u;          x1 += 0x1BD11BF4u;   // ks2+4
  TF_R(13) TF_R(15) TF_R(26) TF_R(6)
  x0 += 0x1BD11BF0u;  x1 += 5u;            // ks0+5
#undef TF_R
  return x0 ^ x1;
}

// ---------- K1: 2-layer MLP in fp64; outputs x64 [h][b] and x_bf16 [b][h] ----------
__global__ void k_mlp(const float* __restrict__ z,  const float* __restrict__ w0,
                      const float* __restrict__ b0, const float* __restrict__ g0,
                      const float* __restrict__ be0, const float* __restrict__ m0,
                      const float* __restrict__ v0,
                      const float* __restrict__ w1, const float* __restrict__ b1,
                      const float* __restrict__ g1, const float* __restrict__ be1,
                      const float* __restrict__ m1, const float* __restrict__ v1,
                      double* __restrict__ x64, unsigned short* __restrict__ x_bf) {
  __shared__ double xs[HID];
  const int b = blockIdx.x, h = threadIdx.x;
  double acc = (double)b0[h];
  for (int k = 0; k < LAT; ++k)
    acc += (double)z[b * LAT + k] * (double)w0[k * HID + h];
  double y = (acc - (double)m0[h]) * (1.0 / sqrt((double)v0[h] + 1e-3)) * (double)g0[h]
             + (double)be0[h];
  y = y > 0.0 ? y : 0.0;
  xs[h] = y;
  __syncthreads();
  double a1 = (double)b1[h];
  for (int k = 0; k < HID; ++k)
    a1 += xs[k] * (double)w1[k * HID + h];
  double y1 = (a1 - (double)m1[h]) * (1.0 / sqrt((double)v1[h] + 1e-3)) * (double)g1[h]
              + (double)be1[h];
  y1 = y1 > 0.0 ? y1 : 0.0;
  x64[h * B + b] = y1;
  x_bf[b * HID + h] = f2bf((float)y1);
}

// ---------- K2: transpose+convert wr/wd [128][25000] f32 -> [25000][128] bf16 ----------
__global__ void k_trans(const float* __restrict__ wr, const float* __restrict__ wd,
                        unsigned short* __restrict__ wrT, unsigned short* __restrict__ wdT) {
  __shared__ float t[64][65];
  const float* src = blockIdx.z ? wd : wr;
  unsigned short* dst = blockIdx.z ? wdT : wrT;
  const int g0 = blockIdx.x * 64, h0 = blockIdx.y * 64;
#pragma unroll
  for (int i = 0; i < 16; ++i) {
    int f = i * 256 + threadIdx.x;
    int hl = f >> 6, gl = f & 63;
    int g = g0 + gl;
    t[hl][gl] = (g < G) ? src[(h0 + hl) * G + g] : 0.f;
  }
  __syncthreads();
#pragma unroll
  for (int i = 0; i < 16; ++i) {
    int f = i * 256 + threadIdx.x;
    int gl = f >> 6, hl = f & 63;
    int g = g0 + gl;
    if (g < G) dst[(size_t)g * HID + h0 + hl] = f2bf(t[hl][gl]);
  }
}

// ---------- K3: rho heads in fp64 + softmax + log; tables [o][b][8] ----------
__global__ void k_rho(const double* __restrict__ x64, const float* __restrict__ wrho,
                      const float* __restrict__ brho,
                      float* __restrict__ pi32, float* __restrict__ lp32,
                      double* __restrict__ lp64) {
  __shared__ float wl[NC * HID * 16];
  const int o0 = blockIdx.x * 16, bB = blockIdx.y * 64;
  for (int i = threadIdx.x; i < NC * HID * 16; i += 256) {
    int ol = i & 15, hh = (i >> 4) & 127, c = i >> 11;
    int o = o0 + ol;
    wl[i] = (o < GB) ? wrho[(c * HID + hh) * GB + o] : 0.f;
  }
  __syncthreads();
  const int lane = threadIdx.x & 63, w = threadIdx.x >> 6;
  const int b = bB + lane;
  double acc[4][NC];
#pragma unroll
  for (int p = 0; p < 4; ++p) {
    int o = o0 + w + 4 * p; int oc = o < GB ? o : GB - 1;
#pragma unroll
    for (int c = 0; c < NC; ++c) acc[p][c] = (double)brho[c * GB + oc];
  }
  for (int h = 0; h < HID; ++h) {
    double xv = x64[h * B + b];
#pragma unroll
    for (int p = 0; p < 4; ++p) {
#pragma unroll
      for (int c = 0; c < NC; ++c)
        acc[p][c] += xv * (double)wl[(c * HID + h) * 16 + (w + 4 * p)];
    }
  }
#pragma unroll
  for (int p = 0; p < 4; ++p) {
    int o = o0 + w + 4 * p;
    if (o >= GB) continue;
    double m = acc[p][0];
#pragma unroll
    for (int c = 1; c < NC; ++c) m = fmax(m, acc[p][c]);
    double e[NC], s = 0.0;
#pragma unroll
    for (int c = 0; c < NC; ++c) { e[c] = exp(acc[p][c] - m); s += e[c]; }
    size_t base = ((size_t)o * B + b) * 8;
#pragma unroll
    for (int c = 0; c < NC; ++c) {
      double pi = e[c] / s;
      double lp = log(pi + 1e-20);
      pi32[base + c] = (float)pi;
      lp32[base + c] = (float)lp;
      lp64[base + c] = lp;
    }
  }
}

// ---------- K4: fused MFMA GEMM (theta, pi_drop) + gumbel sample + all outputs ----------
__global__ __launch_bounds__(256) void k_main(
    const unsigned short* __restrict__ x_bf,
    const unsigned short* __restrict__ wrT, const unsigned short* __restrict__ wdT,
    const float* __restrict__ br, const float* __restrict__ bd,
    const float* __restrict__ wsc, const float* __restrict__ bsc,
    const float* __restrict__ pi32, const float* __restrict__ lp32,
    const double* __restrict__ lp64, float* __restrict__ out) {
  const int tid = threadIdx.x;
  const int wv = tid >> 6, lane = tid & 63;
  const int n = lane & 15, quad = lane >> 4;
  const int gt = wv & 1, btbase = (wv >> 1) * 8;
  const int g = blockIdx.x * 32 + gt * 16 + n;
  const bool gvalid = g < G;
  const int gcl = gvalid ? g : G - 1;
  const float brv = br[gcl], bdv = bd[gcl], wsv = wsc[gcl], bsv = bsc[gcl];
  const int o = gcl / 25;
  const float* lpb = lp32 + ((size_t)o * B) * 8;
  const float* pib = pi32 + ((size_t)o * B) * 8;
  const double* lqb = lp64 + ((size_t)o * B) * 8;

  // B-operand fragments: lane holds W[k = quad*8 + j][g = n] from transposed [g][k]
  short8 fr[4], fd[4];
  {
    const short8* p1 = (const short8*)(wrT + (size_t)gcl * HID + quad * 8);
    const short8* p2 = (const short8*)(wdT + (size_t)gcl * HID + quad * 8);
#pragma unroll
    for (int ks = 0; ks < 4; ++ks) { fr[ks] = p1[ks * 4]; fd[ks] = p2[ks * 4]; }
  }

  for (int bti = 0; bti < 8; ++bti) {
    const int bt = btbase + bti;
    // A-operand: lane holds x[b = bt*16 + n][k = quad*8 + j]
    const short8* xp = (const short8*)(x_bf + (size_t)(bt * 16 + n) * HID + quad * 8);
    f32x4 accr = {0.f, 0.f, 0.f, 0.f}, accd = {0.f, 0.f, 0.f, 0.f};
#pragma unroll
    for (int ks = 0; ks < 4; ++ks) {
      short8 fa = xp[ks * 4];
      accr = __builtin_amdgcn_mfma_f32_16x16x32_bf16(fa, fr[ks], accr, 0, 0, 0);
      accd = __builtin_amdgcn_mfma_f32_16x16x32_bf16(fa, fd[ks], accd, 0, 0, 0);
    }
    // C/D layout: col = lane&15 (== g lane n), row = quad*4 + i
#pragma unroll
    for (int i = 0; i < 4; ++i) {
      const int b = bt * 16 + quad * 4 + i;
      const float th = expf(accr[i] + brv);
      const float pd = accd[i] + bdv;
      const float* lpp = lpb + (size_t)b * 8;
      f32x4 l0 = *(const f32x4*)lpp;
      f32x4 l1 = *(const f32x4*)(lpp + 4);
      float lpv[8];
      lpv[0] = l0[0]; lpv[1] = l0[1]; lpv[2] = l0[2]; lpv[3] = l0[3];
      lpv[4] = l1[0]; lpv[5] = l1[1]; lpv[6] = l1[2]; lpv[7] = l1[3];
      unsigned int bits[NC];
      const unsigned int idx0 = (unsigned int)b * 175000u + (unsigned int)g * 7u;
      float best = -3.4e38f, sec = -3.4e38f; int arg = 0;
#pragma unroll
      for (int c = 0; c < NC; ++c) {
        unsigned int bb = threefry_xor(idx0 + (unsigned int)c);
        bits[c] = bb;
        float uf = __uint_as_float((bb >> 9) | 0x3f800000u) - 1.0f;
        float gn = -logf(-logf(uf + 1e-20f) + 1e-20f);
        float mv = lpv[c] + gn;
        if (mv > best) { sec = best; best = mv; arg = c; }
        else if (mv > sec) sec = mv;
      }
      int s = arg;
      if (best - sec < 2e-3f) {              // rare fp64 slow path (~1e-3 of genes)
        const double* lq = lqb + (size_t)b * 8;
        double lv[NC], bestd = -1e300;
#pragma unroll
        for (int c = 0; c < NC; ++c) {
          float uf = __uint_as_float((bits[c] >> 9) | 0x3f800000u) - 1.0f;
          double gn = -log(-log((double)uf + 1e-20) + 1e-20);
          lv[c] = lq[c] + gn;
          bestd = fmax(bestd, lv[c]);
        }
        s = 0;
#pragma unroll
        for (int c = 0; c < NC; ++c) if (lv[c] == bestd) s += c;  // exact-tie => sum (matches y==max)
      }
      if (gvalid) {
        const float smp = (float)s;
        const float mu = 1.f / (1.f + expf(-(smp * wsv + bsv)));
        const size_t og = (size_t)b * G + g;
        out[og] = mu;                    // mu
        out[6400000 + og] = th;          // theta
        out[12800000 + og] = pd;         // pi_drop
        out[19200000 + og] = smp;        // sample
        const float* pip = pib + (size_t)b * 8;
        f32x4 p0 = *(const f32x4*)pip;
        f32x4 p1v = *(const f32x4*)(pip + 4);
        const size_t pbo = 25600000 + og * 7;   // pi [B][G][C]
        out[pbo + 0] = p0[0]; out[pbo + 1] = p0[1]; out[pbo + 2] = p0[2]; out[pbo + 3] = p0[3];
        out[pbo + 4] = p1v[0]; out[pbo + 5] = p1v[1]; out[pbo + 6] = p1v[2];
      }
    }
  }
}

extern "C" void kernel_launch(void* const* d_in, const int* in_sizes, int n_in,
                              void* d_out, int out_size, void* d_ws, size_t ws_size,
                              hipStream_t stream) {
  const float* z   = (const float*)d_in[0];
  const float* w0  = (const float*)d_in[1];
  const float* b0  = (const float*)d_in[2];
  const float* g0  = (const float*)d_in[3];
  const float* be0 = (const float*)d_in[4];
  const float* m0  = (const float*)d_in[5];
  const float* v0  = (const float*)d_in[6];
  const float* w1  = (const float*)d_in[7];
  const float* b1  = (const float*)d_in[8];
  const float* g1  = (const float*)d_in[9];
  const float* be1 = (const float*)d_in[10];
  const float* m1  = (const float*)d_in[11];
  const float* v1  = (const float*)d_in[12];
  const float* wr  = (const float*)d_in[13];
  const float* br  = (const float*)d_in[14];
  const float* wd  = (const float*)d_in[15];
  const float* bd  = (const float*)d_in[16];
  const float* wrho= (const float*)d_in[17];
  const float* brho= (const float*)d_in[18];
  const float* wsc = (const float*)d_in[19];
  const float* bsc = (const float*)d_in[20];

  char* ws = (char*)d_ws;
  unsigned short* x_bf = (unsigned short*)(ws);            //  65,536 B
  double* x64          = (double*)(ws + 65536);            // 262,144 B
  unsigned short* wrT  = (unsigned short*)(ws + 327680);   // 6.4 MB
  unsigned short* wdT  = (unsigned short*)(ws + 6727680);  // 6.4 MB
  float* pi32          = (float*)(ws + 13127680);          // 8.192 MB
  float* lp32          = (float*)(ws + 21319680);          // 8.192 MB
  double* lp64         = (double*)(ws + 29511680);         // 16.384 MB (total ~43.8 MB)
  float* out = (float*)d_out;

  k_mlp<<<dim3(256), dim3(128), 0, stream>>>(z, w0, b0, g0, be0, m0, v0,
                                             w1, b1, g1, be1, m1, v1, x64, x_bf);
  k_trans<<<dim3(391, 2, 2), dim3(256), 0, stream>>>(wr, wd, wrT, wdT);
  k_rho<<<dim3(63, 4), dim3(256), 0, stream>>>(x64, wrho, brho, pi32, lp32, lp64);
  k_main<<<dim3(782), dim3(256), 0, stream>>>(x_bf, wrT, wdT, br, bd, wsc, bsc,
                                              pi32, lp32, lp64, out);
}

// Round 2
// 550.660 us; speedup vs baseline: 1.1519x; 1.1519x over previous
//
#include <hip/hip_runtime.h>

#define B 256
#define LAT 20
#define HID 128
#define G 25000
#define GB 1000
#define NC 7

typedef __attribute__((ext_vector_type(8))) short short8;
typedef __attribute__((ext_vector_type(4))) float f32x4;

__device__ __forceinline__ unsigned short f2bf(float f) {
  unsigned int u = __float_as_uint(f);
  u += 0x7fffu + ((u >> 16) & 1u);   // round-to-nearest-even
  return (unsigned short)(u >> 16);
}

// threefry2x32 with key (0,42), x0=0 (hi word of flat index), x1=idx (lo word),
// partitionable-mode output fold o0^o1. ks = [0, 42, 0x1BD11BF0].
__device__ __forceinline__ unsigned int threefry_xor(unsigned int idx) {
  unsigned int x0 = 0u;
  unsigned int x1 = idx + 42u;
#define TF_R(r) { x0 += x1; x1 = (x1 << r) | (x1 >> (32 - r)); x1 ^= x0; }
  TF_R(13) TF_R(15) TF_R(26) TF_R(6)
  x0 += 42u;          x1 += 0x1BD11BF1u;   // ks2+1
  TF_R(17) TF_R(29) TF_R(16) TF_R(24)
  x0 += 0x1BD11BF0u;  x1 += 2u;            // ks0+2
  TF_R(13) TF_R(15) TF_R(26) TF_R(6)
  /* x0 += ks0 = 0 */ x1 += 45u;           // ks1+3
  TF_R(17) TF_R(29) TF_R(16) TF_R(24)
  x0 += 42u;          x1 += 0x1BD11BF4u;   // ks2+4
  TF_R(13) TF_R(15) TF_R(26) TF_R(6)
  x0 += 0x1BD11BF0u;  x1 += 5u;            // ks0+5
#undef TF_R
  return x0 ^ x1;
}

// ---------- K1: 2-layer MLP in fp64; outputs x64 [h][b] and x_bf16 [b][h] ----------
__global__ void k_mlp(const float* __restrict__ z,  const float* __restrict__ w0,
                      const float* __restrict__ b0, const float* __restrict__ g0,
                      const float* __restrict__ be0, const float* __restrict__ m0,
                      const float* __restrict__ v0,
                      const float* __restrict__ w1, const float* __restrict__ b1,
                      const float* __restrict__ g1, const float* __restrict__ be1,
                      const float* __restrict__ m1, const float* __restrict__ v1,
                      double* __restrict__ x64, unsigned short* __restrict__ x_bf) {
  __shared__ double xs[HID];
  const int b = blockIdx.x, h = threadIdx.x;
  double acc = (double)b0[h];
  for (int k = 0; k < LAT; ++k)
    acc += (double)z[b * LAT + k] * (double)w0[k * HID + h];
  double y = (acc - (double)m0[h]) * (1.0 / sqrt((double)v0[h] + 1e-3)) * (double)g0[h]
             + (double)be0[h];
  y = y > 0.0 ? y : 0.0;
  xs[h] = y;
  __syncthreads();
  double a1 = (double)b1[h];
  for (int k = 0; k < HID; ++k)
    a1 += xs[k] * (double)w1[k * HID + h];
  double y1 = (a1 - (double)m1[h]) * (1.0 / sqrt((double)v1[h] + 1e-3)) * (double)g1[h]
              + (double)be1[h];
  y1 = y1 > 0.0 ? y1 : 0.0;
  x64[h * B + b] = y1;
  x_bf[b * HID + h] = f2bf((float)y1);
}

// ---------- K2: transpose+convert wr/wd [128][25000] f32 -> [25000][128] bf16 ----------
__global__ void k_trans(const float* __restrict__ wr, const float* __restrict__ wd,
                        unsigned short* __restrict__ wrT, unsigned short* __restrict__ wdT) {
  __shared__ float t[64][65];
  const float* src = blockIdx.z ? wd : wr;
  unsigned short* dst = blockIdx.z ? wdT : wrT;
  const int g0 = blockIdx.x * 64, h0 = blockIdx.y * 64;
#pragma unroll
  for (int i = 0; i < 16; ++i) {
    int f = i * 256 + threadIdx.x;
    int hl = f >> 6, gl = f & 63;
    int g = g0 + gl;
    t[hl][gl] = (g < G) ? src[(h0 + hl) * G + g] : 0.f;
  }
  __syncthreads();
#pragma unroll
  for (int i = 0; i < 16; ++i) {
    int f = i * 256 + threadIdx.x;
    int gl = f >> 6, hl = f & 63;
    int g = g0 + gl;
    if (g < G) dst[(size_t)g * HID + h0 + hl] = f2bf(t[hl][gl]);
  }
}

// ---------- K3: rho heads in fp64 + softmax + log; tables [o][c][b] ----------
__global__ __launch_bounds__(256) void k_rho(const double* __restrict__ x64,
                      const float* __restrict__ wrho, const float* __restrict__ brho,
                      float* __restrict__ pi32, float* __restrict__ lp32,
                      double* __restrict__ lp64) {
  __shared__ float wl[NC * HID * 4];   // [c][h][ol], 14336 B
  const int o0 = blockIdx.x * 4, bB = blockIdx.y * 64;
  for (int i = threadIdx.x; i < NC * HID * 4; i += 256) {
    int ol = i & 3, rest = i >> 2;     // rest = c*128 + h
    int c = rest >> 7, h = rest & 127;
    wl[i] = wrho[(c * HID + h) * GB + o0 + ol];
  }
  __syncthreads();
  const int lane = threadIdx.x & 63, ol = threadIdx.x >> 6;
  const int b = bB + lane, o = o0 + ol;
  double acc[NC];
#pragma unroll
  for (int c = 0; c < NC; ++c) acc[c] = (double)brho[c * GB + o];
  for (int h = 0; h < HID; ++h) {
    double xv = x64[h * B + b];
#pragma unroll
    for (int c = 0; c < NC; ++c)
      acc[c] += xv * (double)wl[(c * HID + h) * 4 + ol];
  }
  double m = acc[0];
#pragma unroll
  for (int c = 1; c < NC; ++c) m = fmax(m, acc[c]);
  double e[NC], s = 0.0;
#pragma unroll
  for (int c = 0; c < NC; ++c) { e[c] = exp(acc[c] - m); s += e[c]; }
  const size_t base = (size_t)o * (NC * B) + b;
#pragma unroll
  for (int c = 0; c < NC; ++c) {
    double pi = e[c] / s;
    double lp = log(pi + 1e-20);
    pi32[base + c * B] = (float)pi;
    lp32[base + c * B] = (float)lp;
    lp64[base + c * B] = lp;
  }
}

// ---------- K4: fused MFMA GEMM (theta, pi_drop) + gumbel sample + all outputs ----------
__global__ __launch_bounds__(256) void k_main(
    const unsigned short* __restrict__ x_bf,
    const unsigned short* __restrict__ wrT, const unsigned short* __restrict__ wdT,
    const float* __restrict__ br, const float* __restrict__ bd,
    const float* __restrict__ wsc, const float* __restrict__ bsc,
    const float* __restrict__ pi32, const float* __restrict__ lp32,
    const double* __restrict__ lp64, float* __restrict__ out) {
  const int tid = threadIdx.x;
  const int wv = tid >> 6, lane = tid & 63;
  const int n = lane & 15, quad = lane >> 4;
  const int gt = wv & 1;
  const int btbase = blockIdx.y * 8 + (wv >> 1) * 4;   // batch-split across blockIdx.y
  const int g = blockIdx.x * 32 + gt * 16 + n;
  const bool gvalid = g < G;
  const int gcl = gvalid ? g : G - 1;
  const float brv = br[gcl], bdv = bd[gcl], wsv = wsc[gcl], bsv = bsc[gcl];
  const int o = gcl / 25;
  const float*  lpb = lp32 + (size_t)o * (NC * B);
  const float*  pib = pi32 + (size_t)o * (NC * B);
  const double* lqb = lp64 + (size_t)o * (NC * B);

  // B-operand fragments: lane holds W[k = quad*8 + j][g = n] from transposed [g][k]
  short8 fr[4], fd[4];
  {
    const short8* p1 = (const short8*)(wrT + (size_t)gcl * HID + quad * 8);
    const short8* p2 = (const short8*)(wdT + (size_t)gcl * HID + quad * 8);
#pragma unroll
    for (int ks = 0; ks < 4; ++ks) { fr[ks] = p1[ks * 4]; fd[ks] = p2[ks * 4]; }
  }

  for (int bti = 0; bti < 4; ++bti) {
    const int bt = btbase + bti;
    // A-operand: lane holds x[b = bt*16 + n][k = quad*8 + j]
    const short8* xp = (const short8*)(x_bf + (size_t)(bt * 16 + n) * HID + quad * 8);
    f32x4 accr = {0.f, 0.f, 0.f, 0.f}, accd = {0.f, 0.f, 0.f, 0.f};
#pragma unroll
    for (int ks = 0; ks < 4; ++ks) {
      short8 fa = xp[ks * 4];
      accr = __builtin_amdgcn_mfma_f32_16x16x32_bf16(fa, fr[ks], accr, 0, 0, 0);
      accd = __builtin_amdgcn_mfma_f32_16x16x32_bf16(fa, fd[ks], accd, 0, 0, 0);
    }
    // C/D layout: col = lane&15 (== g lane n), row = quad*4 + i
#pragma unroll
    for (int i = 0; i < 4; ++i) {
      const int b = bt * 16 + quad * 4 + i;
      const float th = expf(accr[i] + brv);
      const float pd = accd[i] + bdv;
      float lpv[NC];
#pragma unroll
      for (int c = 0; c < NC; ++c) lpv[c] = lpb[c * B + b];   // broadcast across gene-lanes
      unsigned int bits[NC];
      const unsigned int idx0 = (unsigned int)b * 175000u + (unsigned int)g * 7u;
      float best = -3.4e38f, sec = -3.4e38f; int arg = 0;
#pragma unroll
      for (int c = 0; c < NC; ++c) {
        unsigned int bb = threefry_xor(idx0 + (unsigned int)c);
        bits[c] = bb;
        float uf = __uint_as_float((bb >> 9) | 0x3f800000u) - 1.0f;
        float l1 = -logf(uf + 1e-20f);          // inner log: precise (result can be ~1e-7)
        float gn = -__logf(l1 + 1e-20f);        // outer log: native, result O(1)
        float mv = lpv[c] + gn;
        if (mv > best) { sec = best; best = mv; arg = c; }
        else if (mv > sec) sec = mv;
      }
      int s = arg;
      if (best - sec < 2e-3f) {              // rare fp64 slow path
        double lv[NC], bestd = -1e300;
#pragma unroll
        for (int c = 0; c < NC; ++c) {
          float uf = __uint_as_float((bits[c] >> 9) | 0x3f800000u) - 1.0f;
          double gn = -log(-log((double)uf + 1e-20) + 1e-20);
          lv[c] = lqb[c * B + b] + gn;
          bestd = fmax(bestd, lv[c]);
        }
        s = 0;
#pragma unroll
        for (int c = 0; c < NC; ++c) if (lv[c] == bestd) s += c;  // exact-tie => sum (matches y==max)
      }
      if (gvalid) {
        const float smp = (float)s;
        const float mu = 1.f / (1.f + expf(-(smp * wsv + bsv)));
        const size_t og = (size_t)b * G + g;
        out[og] = mu;                    // mu
        out[6400000 + og] = th;          // theta
        out[12800000 + og] = pd;         // pi_drop
        out[19200000 + og] = smp;        // sample
        const size_t pbo = 25600000 + og * 7;   // pi [B][G][C]
#pragma unroll
        for (int c = 0; c < NC; ++c) out[pbo + c] = pib[c * B + b];
      }
    }
  }
}

extern "C" void kernel_launch(void* const* d_in, const int* in_sizes, int n_in,
                              void* d_out, int out_size, void* d_ws, size_t ws_size,
                              hipStream_t stream) {
  const float* z   = (const float*)d_in[0];
  const float* w0  = (const float*)d_in[1];
  const float* b0  = (const float*)d_in[2];
  const float* g0  = (const float*)d_in[3];
  const float* be0 = (const float*)d_in[4];
  const float* m0  = (const float*)d_in[5];
  const float* v0  = (const float*)d_in[6];
  const float* w1  = (const float*)d_in[7];
  const float* b1  = (const float*)d_in[8];
  const float* g1  = (const float*)d_in[9];
  const float* be1 = (const float*)d_in[10];
  const float* m1  = (const float*)d_in[11];
  const float* v1  = (const float*)d_in[12];
  const float* wr  = (const float*)d_in[13];
  const float* br  = (const float*)d_in[14];
  const float* wd  = (const float*)d_in[15];
  const float* bd  = (const float*)d_in[16];
  const float* wrho= (const float*)d_in[17];
  const float* brho= (const float*)d_in[18];
  const float* wsc = (const float*)d_in[19];
  const float* bsc = (const float*)d_in[20];

  char* ws = (char*)d_ws;
  unsigned short* x_bf = (unsigned short*)(ws);            //     65,536 B
  double* x64          = (double*)(ws + 65536);            //    262,144 B
  unsigned short* wrT  = (unsigned short*)(ws + 327680);   //  6,400,000 B
  unsigned short* wdT  = (unsigned short*)(ws + 6727680);  //  6,400,000 B
  float* pi32          = (float*)(ws + 13127680);          //  7,168,000 B
  float* lp32          = (float*)(ws + 20295680);          //  7,168,000 B
  double* lp64         = (double*)(ws + 27463680);         // 14,336,000 B  (total ~41.8 MB)
  float* out = (float*)d_out;

  k_mlp<<<dim3(256), dim3(128), 0, stream>>>(z, w0, b0, g0, be0, m0, v0,
                                             w1, b1, g1, be1, m1, v1, x64, x_bf);
  k_trans<<<dim3(391, 2, 2), dim3(256), 0, stream>>>(wr, wd, wrT, wdT);
  k_rho<<<dim3(250, 4), dim3(256), 0, stream>>>(x64, wrho, brho, pi32, lp32, lp64);
  k_main<<<dim3(782, 2), dim3(256), 0, stream>>>(x_bf, wrT, wdT, br, bd, wsc, bsc,
                                                 pi32, lp32, lp64, out);
}

// Round 3
// 522.339 us; speedup vs baseline: 1.2143x; 1.0542x over previous
//
#include <hip/hip_runtime.h>

#define B 256
#define LAT 20
#define HID 128
#define G 25000
#define GB 1000
#define NC 7

typedef __attribute__((ext_vector_type(8))) short short8;
typedef __attribute__((ext_vector_type(4))) float f32x4;

__device__ __forceinline__ unsigned short f2bf(float f) {
  unsigned int u = __float_as_uint(f);
  u += 0x7fffu + ((u >> 16) & 1u);   // round-to-nearest-even
  return (unsigned short)(u >> 16);
}

// threefry2x32 with key (0,42), x0=0 (hi word of flat index), x1=idx (lo word),
// partitionable-mode output fold o0^o1. Verified bit-exact vs harness (R1/R2 pass).
__device__ __forceinline__ unsigned int threefry_xor(unsigned int idx) {
  unsigned int x0 = 0u;
  unsigned int x1 = idx + 42u;
#define TF_R(r) { x0 += x1; x1 = (x1 << r) | (x1 >> (32 - r)); x1 ^= x0; }
  TF_R(13) TF_R(15) TF_R(26) TF_R(6)
  x0 += 42u;          x1 += 0x1BD11BF1u;   // ks2+1
  TF_R(17) TF_R(29) TF_R(16) TF_R(24)
  x0 += 0x1BD11BF0u;  x1 += 2u;            // ks0+2
  TF_R(13) TF_R(15) TF_R(26) TF_R(6)
  /* x0 += ks0 = 0 */ x1 += 45u;           // ks1+3
  TF_R(17) TF_R(29) TF_R(16) TF_R(24)
  x0 += 42u;          x1 += 0x1BD11BF4u;   // ks2+4
  TF_R(13) TF_R(15) TF_R(26) TF_R(6)
  x0 += 0x1BD11BF0u;  x1 += 5u;            // ks0+5
#undef TF_R
  return x0 ^ x1;
}

// ---------- K1: 2-layer MLP in fp64; outputs x64 [h][b] and x_bf16 [b][h] ----------
__global__ void k_mlp(const float* __restrict__ z,  const float* __restrict__ w0,
                      const float* __restrict__ b0, const float* __restrict__ g0,
                      const float* __restrict__ be0, const float* __restrict__ m0,
                      const float* __restrict__ v0,
                      const float* __restrict__ w1, const float* __restrict__ b1,
                      const float* __restrict__ g1, const float* __restrict__ be1,
                      const float* __restrict__ m1, const float* __restrict__ v1,
                      double* __restrict__ x64, unsigned short* __restrict__ x_bf) {
  __shared__ double xs[HID];
  const int b = blockIdx.x, h = threadIdx.x;
  double acc = (double)b0[h];
  for (int k = 0; k < LAT; ++k)
    acc += (double)z[b * LAT + k] * (double)w0[k * HID + h];
  double y = (acc - (double)m0[h]) * (1.0 / sqrt((double)v0[h] + 1e-3)) * (double)g0[h]
             + (double)be0[h];
  y = y > 0.0 ? y : 0.0;
  xs[h] = y;
  __syncthreads();
  double a1 = (double)b1[h];
  for (int k = 0; k < HID; ++k)
    a1 += xs[k] * (double)w1[k * HID + h];
  double y1 = (a1 - (double)m1[h]) * (1.0 / sqrt((double)v1[h] + 1e-3)) * (double)g1[h]
              + (double)be1[h];
  y1 = y1 > 0.0 ? y1 : 0.0;
  x64[h * B + b] = y1;
  x_bf[b * HID + h] = f2bf((float)y1);
}

// ---------- K2: transpose+convert wr/wd [128][25000] f32 -> [25000][128] bf16 ----------
__global__ void k_trans(const float* __restrict__ wr, const float* __restrict__ wd,
                        unsigned short* __restrict__ wrT, unsigned short* __restrict__ wdT) {
  __shared__ float t[64][65];
  const float* src = blockIdx.z ? wd : wr;
  unsigned short* dst = blockIdx.z ? wdT : wrT;
  const int g0 = blockIdx.x * 64, h0 = blockIdx.y * 64;
#pragma unroll
  for (int i = 0; i < 16; ++i) {
    int f = i * 256 + threadIdx.x;
    int hl = f >> 6, gl = f & 63;
    int g = g0 + gl;
    t[hl][gl] = (g < G) ? src[(h0 + hl) * G + g] : 0.f;
  }
  __syncthreads();
#pragma unroll
  for (int i = 0; i < 16; ++i) {
    int f = i * 256 + threadIdx.x;
    int gl = f >> 6, hl = f & 63;
    int g = g0 + gl;
    if (g < G) dst[(size_t)g * HID + h0 + hl] = f2bf(t[hl][gl]);
  }
}

// ---------- K3: rho heads in fp64 + softmax + log; tables [o][c][b] ----------
__global__ __launch_bounds__(256) void k_rho(const double* __restrict__ x64,
                      const float* __restrict__ wrho, const float* __restrict__ brho,
                      float* __restrict__ pi32, float* __restrict__ lp32,
                      double* __restrict__ lp64) {
  __shared__ float wl[NC * HID * 4];   // [c][h][ol], 14336 B
  const int o0 = blockIdx.x * 4, bB = blockIdx.y * 64;
  for (int i = threadIdx.x; i < NC * HID * 4; i += 256) {
    int ol = i & 3, rest = i >> 2;     // rest = c*128 + h
    int c = rest >> 7, h = rest & 127;
    wl[i] = wrho[(c * HID + h) * GB + o0 + ol];
  }
  __syncthreads();
  const int lane = threadIdx.x & 63, ol = threadIdx.x >> 6;
  const int b = bB + lane, o = o0 + ol;
  double acc[NC];
#pragma unroll
  for (int c = 0; c < NC; ++c) acc[c] = (double)brho[c * GB + o];
  for (int h = 0; h < HID; ++h) {
    double xv = x64[h * B + b];
#pragma unroll
    for (int c = 0; c < NC; ++c)
      acc[c] += xv * (double)wl[(c * HID + h) * 4 + ol];
  }
  double m = acc[0];
#pragma unroll
  for (int c = 1; c < NC; ++c) m = fmax(m, acc[c]);
  double e[NC], s = 0.0;
#pragma unroll
  for (int c = 0; c < NC; ++c) { e[c] = exp(acc[c] - m); s += e[c]; }
  const size_t base = (size_t)o * (NC * B) + b;
#pragma unroll
  for (int c = 0; c < NC; ++c) {
    double pi = e[c] / s;
    double lp = log(pi + 1e-20);
    pi32[base + c * B] = (float)pi;
    lp32[base + c * B] = (float)lp;
    lp64[base + c * B] = lp;
  }
}

// ---------- K4: fused MFMA GEMM (theta, pi_drop) + gumbel sample + all outputs ----------
__global__ __launch_bounds__(256) void k_main(
    const unsigned short* __restrict__ x_bf,
    const unsigned short* __restrict__ wrT, const unsigned short* __restrict__ wdT,
    const float* __restrict__ br, const float* __restrict__ bd,
    const float* __restrict__ wsc, const float* __restrict__ bsc,
    const float* __restrict__ pi32, const float* __restrict__ lp32,
    const double* __restrict__ lp64, float* __restrict__ out) {
  __shared__ float s_lp[3 * NC * 128];   // [o_local][c][b_local], 10752 B
  __shared__ float s_pi[3 * NC * 128];   // 10752 B
  const int tid = threadIdx.x;
  const int o_base = (blockIdx.x * 32) / 25;
  const int bB = blockIdx.y * 128;

  // Stage the <=3 o-slabs of lp32/pi32 this block touches (coalesced, L2-hot)
  for (int i = tid; i < 3 * NC * 128; i += 256) {
    int ol = i / (NC * 128);
    int r = i - ol * (NC * 128);         // c*128 + bl
    int c = r >> 7, bl = r & 127;
    int oo = o_base + ol; if (oo > GB - 1) oo = GB - 1;
    size_t src = (size_t)oo * (NC * B) + c * B + bB + bl;
    s_lp[i] = lp32[src];
    s_pi[i] = pi32[src];
  }

  const int wv = tid >> 6, lane = tid & 63;
  const int n = lane & 15, quad = lane >> 4;
  const int gt = wv & 1;
  const int btbase = blockIdx.y * 8 + (wv >> 1) * 4;
  const int g = blockIdx.x * 32 + gt * 16 + n;
  const bool gvalid = g < G;
  const int gcl = gvalid ? g : G - 1;
  const float brv = br[gcl], bdv = bd[gcl], wsv = wsc[gcl], bsv = bsc[gcl];
  const int o = gcl / 25;
  const int o_local = o - o_base;
  const double* lqb = lp64 + (size_t)o * (NC * B);

  // B-operand fragments: lane holds W[k = quad*8 + j][g = n] from transposed [g][k]
  short8 fr[4], fd[4];
  {
    const short8* p1 = (const short8*)(wrT + (size_t)gcl * HID + quad * 8);
    const short8* p2 = (const short8*)(wdT + (size_t)gcl * HID + quad * 8);
#pragma unroll
    for (int ks = 0; ks < 4; ++ks) { fr[ks] = p1[ks * 4]; fd[ks] = p2[ks * 4]; }
  }
  __syncthreads();

  for (int bti = 0; bti < 4; ++bti) {
    const int bt = btbase + bti;
    // A-operand: lane holds x[b = bt*16 + n][k = quad*8 + j]
    const short8* xp = (const short8*)(x_bf + (size_t)(bt * 16 + n) * HID + quad * 8);
    f32x4 accr = {0.f, 0.f, 0.f, 0.f}, accd = {0.f, 0.f, 0.f, 0.f};
#pragma unroll
    for (int ks = 0; ks < 4; ++ks) {
      short8 fa = xp[ks * 4];
      accr = __builtin_amdgcn_mfma_f32_16x16x32_bf16(fa, fr[ks], accr, 0, 0, 0);
      accd = __builtin_amdgcn_mfma_f32_16x16x32_bf16(fa, fd[ks], accd, 0, 0, 0);
    }
    // C/D layout: col = lane&15 (== g lane n), row = quad*4 + i
#pragma unroll
    for (int i = 0; i < 4; ++i) {
      const int b = bt * 16 + quad * 4 + i;
      const int b_local = (wv >> 1) * 64 + bti * 16 + quad * 4 + i;
      const float th = __expf(accr[i] + brv);
      const float pd = accd[i] + bdv;
      const float* lpp = s_lp + o_local * (NC * 128) + b_local;
      unsigned int bits[NC];
      const unsigned int idx0 = (unsigned int)b * 175000u + (unsigned int)g * 7u;
      float best = -3.4e38f, sec = -3.4e38f; int arg = 0;
#pragma unroll
      for (int c = 0; c < NC; ++c) {
        unsigned int bb = threefry_xor(idx0 + (unsigned int)c);
        bits[c] = bb;
        float uf = __uint_as_float((bb >> 9) | 0x3f800000u) - 1.0f;  // u in [0,1)
        // l1 = -log(u+1e-20): native log, with log1p series when u -> 1
        // (native v_log_f32 abs error near 1 would blow up the gumbel)
        float v1m = 1.0f - uf;                        // exact for uf >= 0.5
        float ln_nat = -__logf(uf + 1e-20f);
        float ln_ser = v1m * (1.0f + v1m * (0.5f + 0.33333334f * v1m));
        float l1 = (v1m < 0.001953125f) ? ln_ser : ln_nat;
        float gn = -__logf(l1);                       // l1 >= ~1.19e-7 > 0
        float mv = lpp[c * 128] + gn;
        if (mv > best) { sec = best; best = mv; arg = c; }
        else if (mv > sec) sec = mv;
      }
      int s = arg;
      if (best - sec < 3e-4f) {              // rare fp64 slow path (~3e-4 of genes)
        double lv[NC], bestd = -1e300;
#pragma unroll
        for (int c = 0; c < NC; ++c) {
          float uf = __uint_as_float((bits[c] >> 9) | 0x3f800000u) - 1.0f;
          double gn = -log(-log((double)uf + 1e-20) + 1e-20);
          lv[c] = lqb[c * B + b] + gn;
          bestd = fmax(bestd, lv[c]);
        }
        s = 0;
#pragma unroll
        for (int c = 0; c < NC; ++c) if (lv[c] == bestd) s += c;  // exact-tie => sum (matches y==max)
      }
      if (gvalid) {
        const float smp = (float)s;
        const float mu = __builtin_amdgcn_rcpf(1.f + __expf(-(smp * wsv + bsv)));
        const size_t og = (size_t)b * G + g;
        out[og] = mu;                    // mu
        out[6400000 + og] = th;          // theta
        out[12800000 + og] = pd;         // pi_drop
        out[19200000 + og] = smp;        // sample
        const float* pip = s_pi + o_local * (NC * 128) + b_local;
        const size_t pbo = 25600000 + og * 7;   // pi [B][G][C]
#pragma unroll
        for (int c = 0; c < NC; ++c) out[pbo + c] = pip[c * 128];
      }
    }
  }
}

extern "C" void kernel_launch(void* const* d_in, const int* in_sizes, int n_in,
                              void* d_out, int out_size, void* d_ws, size_t ws_size,
                              hipStream_t stream) {
  const float* z   = (const float*)d_in[0];
  const float* w0  = (const float*)d_in[1];
  const float* b0  = (const float*)d_in[2];
  const float* g0  = (const float*)d_in[3];
  const float* be0 = (const float*)d_in[4];
  const float* m0  = (const float*)d_in[5];
  const float* v0  = (const float*)d_in[6];
  const float* w1  = (const float*)d_in[7];
  const float* b1  = (const float*)d_in[8];
  const float* g1  = (const float*)d_in[9];
  const float* be1 = (const float*)d_in[10];
  const float* m1  = (const float*)d_in[11];
  const float* v1  = (const float*)d_in[12];
  const float* wr  = (const float*)d_in[13];
  const float* br  = (const float*)d_in[14];
  const float* wd  = (const float*)d_in[15];
  const float* bd  = (const float*)d_in[16];
  const float* wrho= (const float*)d_in[17];
  const float* brho= (const float*)d_in[18];
  const float* wsc = (const float*)d_in[19];
  const float* bsc = (const float*)d_in[20];

  char* ws = (char*)d_ws;
  unsigned short* x_bf = (unsigned short*)(ws);            //     65,536 B
  double* x64          = (double*)(ws + 65536);            //    262,144 B
  unsigned short* wrT  = (unsigned short*)(ws + 327680);   //  6,400,000 B
  unsigned short* wdT  = (unsigned short*)(ws + 6727680);  //  6,400,000 B
  float* pi32          = (float*)(ws + 13127680);          //  7,168,000 B
  float* lp32          = (float*)(ws + 20295680);          //  7,168,000 B
  double* lp64         = (double*)(ws + 27463680);         // 14,336,000 B  (total ~41.8 MB)
  float* out = (float*)d_out;

  k_mlp<<<dim3(256), dim3(128), 0, stream>>>(z, w0, b0, g0, be0, m0, v0,
                                             w1, b1, g1, be1, m1, v1, x64, x_bf);
  k_trans<<<dim3(391, 2, 2), dim3(256), 0, stream>>>(wr, wd, wrT, wdT);
  k_rho<<<dim3(250, 4), dim3(256), 0, stream>>>(x64, wrho, brho, pi32, lp32, lp64);
  k_main<<<dim3(782, 2), dim3(256), 0, stream>>>(x_bf, wrT, wdT, br, bd, wsc, bsc,
                                                 pi32, lp32, lp64, out);
}